// Round 1
// baseline (6494.187 us; speedup 1.0000x reference)
//
#include <hip/hip_runtime.h>
#include <math.h>

#define B 4
#define CG 256
#define CM 128   // Cg/2
#define CA 128
#define H 128
#define W_ 128
#define HS 64
#define WS 64
#define L 4096
#define D1 1152  // CM*9
#define D2 2048  // CA*16

__device__ __forceinline__ int refl(int i, int n) {
    return i < 0 ? -i : (i >= n ? 2 * n - 2 - i : i);
}

// K0: f_ds[b,co,hs,ws] = sum_ci gc_w[co,ci]*f[b,ci,2hs,2ws] + gc_b[co]
__global__ __launch_bounds__(256) void k_conv_ds(const float* __restrict__ f,
                                                 const float* __restrict__ gw,
                                                 const float* __restrict__ gb,
                                                 float* __restrict__ fds) {
    int ws = threadIdx.x;                      // 0..63
    int co = blockIdx.y * 4 + threadIdx.y;     // 0..127
    int hs = blockIdx.x;                       // 0..63
    int b  = blockIdx.z;
    const float* fp  = f + (size_t)b * CG * H * W_ + (2 * hs) * W_ + 2 * ws;
    const float* gwp = gw + co * CG;
    float acc = gb[co];
#pragma unroll 4
    for (int ci = 0; ci < CG; ++ci) acc += gwp[ci] * fp[(size_t)ci * H * W_];
    fds[(((size_t)b * CM + co) * HS + hs) * WS + ws] = acc;
}

// K1: ssq[b,hs,ws] = sum_c f_ds^2
__global__ __launch_bounds__(64) void k_ssq(const float* __restrict__ fds,
                                            float* __restrict__ ssq) {
    int ws = threadIdx.x, hs = blockIdx.x, b = blockIdx.y;
    float s = 0.f;
    for (int c = 0; c < CM; ++c) {
        float v = fds[(((size_t)b * CM + c) * HS + hs) * WS + ws];
        s += v * v;
    }
    ssq[((size_t)b * HS + hs) * WS + ws] = s;
}

// K2: u_mean -> su, sk ; writes softmax_scale output and ws copy
__global__ __launch_bounds__(256) void k_scale(const float* __restrict__ unk,
                                               float* __restrict__ suk,
                                               float* __restrict__ out2) {
    int b = blockIdx.x, t = threadIdx.x;
    __shared__ float red[256];
    float s = 0.f;
    for (int i = t; i < L; i += 256) {
        int hs = i >> 6, ws = i & 63;
        s += unk[(size_t)b * H * W_ + (2 * hs) * W_ + 2 * ws];
    }
    red[t] = s;
    __syncthreads();
    for (int o = 128; o > 0; o >>= 1) {
        if (t < o) red[t] += red[t + o];
        __syncthreads();
    }
    if (t == 0) {
        float u = red[0] / (float)L;
        float k = 1.0f - u;
        float su = sqrtf(u / k); su = fminf(fmaxf(su, 0.1f), 10.0f);
        float sk = sqrtf(k / u); sk = fminf(fmaxf(sk, 0.1f), 10.0f);
        suk[b * 2] = su; suk[b * 2 + 1] = sk;
        out2[b * 2] = su; out2[b * 2 + 1] = sk;
    }
}

// K3: per (b,q): g = gate/max(norm,1e-4), dg = -10000*mm
__global__ __launch_bounds__(64) void k_gate(const float* __restrict__ unk,
                                             const float* __restrict__ ssq,
                                             const float* __restrict__ suk,
                                             float* __restrict__ g,
                                             float* __restrict__ dg) {
    int ws = threadIdx.x, hs = blockIdx.x, b = blockIdx.y;
    float sm = 0.f, sq = 0.f;
    for (int di = -1; di <= 1; ++di) {
        int rh = refl(hs + di, HS);
        for (int dj = -1; dj <= 1; ++dj) {
            int rw = refl(ws + dj, WS);
            sm += unk[(size_t)b * H * W_ + (2 * rh) * W_ + 2 * rw];
            sq += ssq[((size_t)b * HS + rh) * WS + rw];
        }
    }
    float mm   = (sm > 0.0f) ? 1.0f : 0.0f;
    float norm = sqrtf(sq);
    float gate = (mm > 0.0f) ? suk[2 * b] : suk[2 * b + 1];
    int q = hs * WS + ws;
    g[(size_t)b * L + q]  = gate / fmaxf(norm, 1e-4f);
    dg[(size_t)b * L + q] = -10000.0f * mm;
}

// K4: W[q, c*9+i*3+j] = f_ds[b,c, refl(hs+i-1), refl(ws+j-1)]
__global__ __launch_bounds__(256) void k_buildW(const float* __restrict__ fds,
                                                float* __restrict__ Wm, int b) {
    int ws = threadIdx.x;
    int c  = blockIdx.y * 4 + threadIdx.y;
    int hs = blockIdx.x;
    int q  = hs * WS + ws;
    float* dst = Wm + (size_t)q * D1 + c * 9;
    const float* src = fds + ((size_t)b * CM + c) * HS * WS;
#pragma unroll
    for (int i = 0; i < 3; ++i) {
        int rh = refl(hs + i - 1, HS);
#pragma unroll
        for (int j = 0; j < 3; ++j) {
            int rw = refl(ws + j - 1, WS);
            dst[i * 3 + j] = src[rh * WS + rw];
        }
    }
}

// K5: ST[p,q] = (W[p].W[q]) * g[q] + (p==q ? dg[q] : 0)   (fp32, 128x128x8 tile)
__global__ __launch_bounds__(256) void k_gemm1(const float* __restrict__ Wm,
                                               const float* __restrict__ g,
                                               const float* __restrict__ dg,
                                               float* __restrict__ ST) {
    __shared__ float As[8][128];
    __shared__ float Bs[8][128];
    int tid   = threadIdx.x;
    int pBase = blockIdx.y * 128, qBase = blockIdx.x * 128;
    int row = tid & 127, kh = tid >> 7;
    int tr = tid >> 4, tc = tid & 15;
    float acc[8][8];
#pragma unroll
    for (int i = 0; i < 8; ++i)
#pragma unroll
        for (int j = 0; j < 8; ++j) acc[i][j] = 0.f;

    for (int k0 = 0; k0 < D1; k0 += 8) {
        float4 av = *(const float4*)(Wm + (size_t)(pBase + row) * D1 + k0 + kh * 4);
        float4 bv = *(const float4*)(Wm + (size_t)(qBase + row) * D1 + k0 + kh * 4);
        __syncthreads();
        As[kh * 4 + 0][row] = av.x; As[kh * 4 + 1][row] = av.y;
        As[kh * 4 + 2][row] = av.z; As[kh * 4 + 3][row] = av.w;
        Bs[kh * 4 + 0][row] = bv.x; Bs[kh * 4 + 1][row] = bv.y;
        Bs[kh * 4 + 2][row] = bv.z; Bs[kh * 4 + 3][row] = bv.w;
        __syncthreads();
#pragma unroll
        for (int kk = 0; kk < 8; ++kk) {
            float4 a0 = *(const float4*)&As[kk][tr * 8];
            float4 a1 = *(const float4*)&As[kk][tr * 8 + 4];
            float4 b0 = *(const float4*)&Bs[kk][tc * 8];
            float4 b1 = *(const float4*)&Bs[kk][tc * 8 + 4];
            float a[8]  = {a0.x, a0.y, a0.z, a0.w, a1.x, a1.y, a1.z, a1.w};
            float bb[8] = {b0.x, b0.y, b0.z, b0.w, b1.x, b1.y, b1.z, b1.w};
#pragma unroll
            for (int i = 0; i < 8; ++i)
#pragma unroll
                for (int j = 0; j < 8; ++j) acc[i][j] += a[i] * bb[j];
        }
    }
    float gq[8];
#pragma unroll
    for (int j = 0; j < 8; ++j) gq[j] = g[qBase + tc * 8 + j];
#pragma unroll
    for (int i = 0; i < 8; ++i) {
        int p = pBase + tr * 8 + i;
        float out[8];
#pragma unroll
        for (int j = 0; j < 8; ++j) {
            int q = qBase + tc * 8 + j;
            float v = acc[i][j] * gq[j];
            if (p == q) v += dg[q];
            out[j] = v;
        }
        *(float4*)(ST + (size_t)p * L + qBase + tc * 8) =
            make_float4(out[0], out[1], out[2], out[3]);
        *(float4*)(ST + (size_t)p * L + qBase + tc * 8 + 4) =
            make_float4(out[4], out[5], out[6], out[7]);
    }
}

// K6: per row p: argmax (first-max) -> offsets; softmax in place
__global__ __launch_bounds__(256) void k_softmax(float* __restrict__ ST,
                                                 float* __restrict__ out1, int b) {
    __shared__ float buf[4096];
    __shared__ float rmax[256];
    __shared__ int   ridx[256];
    __shared__ float rsum[256];
    int p = blockIdx.x, t = threadIdx.x;
    float* rowp = ST + (size_t)p * L;
    float mx = -3.402823466e38f;
    int   mi = 0;
    for (int i = t; i < L; i += 256) {
        float v = rowp[i];
        buf[i] = v;
        if (v > mx) { mx = v; mi = i; }
    }
    rmax[t] = mx; ridx[t] = mi;
    __syncthreads();
    for (int o = 128; o > 0; o >>= 1) {
        if (t < o) {
            float v1 = rmax[t], v2 = rmax[t + o];
            int   i1 = ridx[t], i2 = ridx[t + o];
            if (v2 > v1 || (v2 == v1 && i2 < i1)) { rmax[t] = v2; ridx[t] = i2; }
        }
        __syncthreads();
    }
    float gmax = rmax[0];
    int   gidx = ridx[0];
    float s = 0.f;
    for (int i = t; i < L; i += 256) s += __expf(buf[i] - gmax);
    rsum[t] = s;
    __syncthreads();
    for (int o = 128; o > 0; o >>= 1) {
        if (t < o) rsum[t] += rsum[t + o];
        __syncthreads();
    }
    float inv = 1.0f / rsum[0];
    for (int i = t; i < L; i += 256) rowp[i] = __expf(buf[i] - gmax) * inv;
    if (t == 0) {
        out1[(size_t)(b * 2 + 0) * L + p] = (float)(gidx / WS - 32);
        out1[(size_t)(b * 2 + 1) * L + p] = (float)(gidx % WS - 32);
    }
}

// K7: A[q, c*16+ki*4+kj] = alpha[b,c, refl(2hs+ki-1), refl(2ws+kj-1)]
__global__ __launch_bounds__(256) void k_buildA(const float* __restrict__ alpha,
                                                float* __restrict__ Am, int b) {
    int ws = threadIdx.x;
    int c  = blockIdx.y * 4 + threadIdx.y;
    int hs = blockIdx.x;
    int q  = hs * WS + ws;
    float* dst = Am + (size_t)q * D2 + c * 16;
    const float* src = alpha + ((size_t)b * CA + c) * H * W_;
#pragma unroll
    for (int ki = 0; ki < 4; ++ki) {
        int rh = refl(2 * hs + ki - 1, H);
#pragma unroll
        for (int kj = 0; kj < 4; ++kj) {
            int rw = refl(2 * ws + kj - 1, W_);
            dst[ki * 4 + kj] = src[rh * W_ + rw];
        }
    }
}

// K8: Z[p,n] = sum_q attnT[p,q]*A[q,n]   (fp32, 128x128x8 tile)
__global__ __launch_bounds__(256) void k_gemm2(const float* __restrict__ At,
                                               const float* __restrict__ Am,
                                               float* __restrict__ Z) {
    __shared__ float As[8][128];
    __shared__ float Bs[8][128];
    int tid   = threadIdx.x;
    int pBase = blockIdx.y * 128, nBase = blockIdx.x * 128;
    int row = tid & 127, kh = tid >> 7;
    int ln = (tid & 31) * 4, lk = tid >> 5;
    int tr = tid >> 4, tc = tid & 15;
    float acc[8][8];
#pragma unroll
    for (int i = 0; i < 8; ++i)
#pragma unroll
        for (int j = 0; j < 8; ++j) acc[i][j] = 0.f;

    for (int k0 = 0; k0 < L; k0 += 8) {
        float4 av = *(const float4*)(At + (size_t)(pBase + row) * L + k0 + kh * 4);
        float4 bv = *(const float4*)(Am + (size_t)(k0 + lk) * D2 + nBase + ln);
        __syncthreads();
        As[kh * 4 + 0][row] = av.x; As[kh * 4 + 1][row] = av.y;
        As[kh * 4 + 2][row] = av.z; As[kh * 4 + 3][row] = av.w;
        *(float4*)&Bs[lk][ln] = bv;
        __syncthreads();
#pragma unroll
        for (int kk = 0; kk < 8; ++kk) {
            float4 a0 = *(const float4*)&As[kk][tr * 8];
            float4 a1 = *(const float4*)&As[kk][tr * 8 + 4];
            float4 b0 = *(const float4*)&Bs[kk][tc * 8];
            float4 b1 = *(const float4*)&Bs[kk][tc * 8 + 4];
            float a[8]  = {a0.x, a0.y, a0.z, a0.w, a1.x, a1.y, a1.z, a1.w};
            float bb[8] = {b0.x, b0.y, b0.z, b0.w, b1.x, b1.y, b1.z, b1.w};
#pragma unroll
            for (int i = 0; i < 8; ++i)
#pragma unroll
                for (int j = 0; j < 8; ++j) acc[i][j] += a[i] * bb[j];
        }
    }
#pragma unroll
    for (int i = 0; i < 8; ++i) {
        *(float4*)(Z + (size_t)(pBase + tr * 8 + i) * D2 + nBase + tc * 8) =
            make_float4(acc[i][0], acc[i][1], acc[i][2], acc[i][3]);
        *(float4*)(Z + (size_t)(pBase + tr * 8 + i) * D2 + nBase + tc * 8 + 4) =
            make_float4(acc[i][4], acc[i][5], acc[i][6], acc[i][7]);
    }
}

// K9: y[b,c,h,w] = 0.25 * sum_{valid ki,kj} Z[(hs*64+ws)*2048 + c*16+ki*4+kj]
__global__ __launch_bounds__(128) void k_gather(const float* __restrict__ Z,
                                                float* __restrict__ yall, int b) {
    int w = threadIdx.x;   // 128
    int h = blockIdx.x;    // 128
    int c = blockIdx.y;    // 128
    float s = 0.f;
#pragma unroll
    for (int ki = 0; ki < 4; ++ki) {
        int num = h + 1 - ki;
        if (num < 0 || (num & 1)) continue;
        int hs = num >> 1;
        if (hs >= HS) continue;
#pragma unroll
        for (int kj = 0; kj < 4; ++kj) {
            int numw = w + 1 - kj;
            if (numw < 0 || (numw & 1)) continue;
            int wsd = numw >> 1;
            if (wsd >= WS) continue;
            s += Z[(size_t)(hs * WS + wsd) * D2 + c * 16 + ki * 4 + kj];
        }
    }
    yall[(((size_t)b * CA + c) * H + h) * W_ + w] = 0.25f * s;
}

// K10: yw[b,o,h,w] = sum_c w_w[o,c]*y[b,c,h,w]
__global__ __launch_bounds__(256) void k_yw(const float* __restrict__ yall,
                                            const float* __restrict__ ww,
                                            float* __restrict__ yw) {
    __shared__ float ybuf[CA * 64];
    int t  = threadIdx.x;
    int w0 = blockIdx.x * 64;
    int h  = blockIdx.y;
    int b  = blockIdx.z;
    for (int idx = t; idx < CA * 64; idx += 256) {
        int c = idx >> 6, w = idx & 63;
        ybuf[idx] = yall[(((size_t)b * CA + c) * H + h) * W_ + w0 + w];
    }
    __syncthreads();
    int w = t & 63, og = t >> 6;
    float acc[32];
#pragma unroll
    for (int r = 0; r < 32; ++r) acc[r] = 0.f;
    for (int c = 0; c < CA; ++c) {
        float yv = ybuf[c * 64 + w];
#pragma unroll
        for (int r = 0; r < 32; ++r) acc[r] += ww[(og + 4 * r) * CA + c] * yv;
    }
#pragma unroll
    for (int r = 0; r < 32; ++r) {
        int o = og + 4 * r;
        yw[(((size_t)b * CA + o) * H + h) * W_ + w0 + w] = acc[r];
    }
}

// K10b: per-channel mean/var over (b,h,w)
__global__ __launch_bounds__(256) void k_stats(const float* __restrict__ yw,
                                               float* __restrict__ meanvar) {
    int o = blockIdx.x, t = threadIdx.x;
    __shared__ float rs[256], rq[256];
    float s = 0.f, q = 0.f;
    for (int b = 0; b < B; ++b) {
        const float* p = yw + ((size_t)(b * CA + o)) * H * W_;
        for (int i = t; i < H * W_; i += 256) {
            float v = p[i];
            s += v;
            q += v * v;
        }
    }
    rs[t] = s; rq[t] = q;
    __syncthreads();
    for (int off = 128; off > 0; off >>= 1) {
        if (t < off) { rs[t] += rs[t + off]; rq[t] += rq[t + off]; }
        __syncthreads();
    }
    if (t == 0) {
        float n = (float)(B * H * W_);
        float mean = rs[0] / n;
        float var  = rq[0] / n - mean * mean;
        meanvar[o] = mean;
        meanvar[CA + o] = var;
    }
}

// K11: out0 = (yw-mean)*rsqrt(var+eps)*gamma + beta + alpha
__global__ __launch_bounds__(256) void k_final(const float* __restrict__ yw,
                                               const float* __restrict__ meanvar,
                                               const float* __restrict__ gamma,
                                               const float* __restrict__ beta,
                                               const float* __restrict__ alpha,
                                               float* __restrict__ out0) {
    size_t i4 = (size_t)blockIdx.x * 256 + threadIdx.x;
    size_t i  = i4 * 4;
    int c = (int)((i >> 14) & 127);
    float4 v = *(const float4*)(yw + i);
    float4 a = *(const float4*)(alpha + i);
    float mean = meanvar[c];
    float var  = meanvar[CA + c];
    float sc   = rsqrtf(var + 1e-5f) * gamma[c];
    float bt   = beta[c];
    float4 r;
    r.x = (v.x - mean) * sc + bt + a.x;
    r.y = (v.y - mean) * sc + bt + a.y;
    r.z = (v.z - mean) * sc + bt + a.z;
    r.w = (v.w - mean) * sc + bt + a.w;
    *(float4*)(out0 + i) = r;
}

extern "C" void kernel_launch(void* const* d_in, const int* in_sizes, int n_in,
                              void* d_out, int out_size, void* d_ws, size_t ws_size,
                              hipStream_t stream) {
    (void)in_sizes; (void)n_in; (void)out_size; (void)ws_size;
    const float* f     = (const float*)d_in[0];
    const float* alpha = (const float*)d_in[1];
    const float* unk   = (const float*)d_in[2];
    const float* gw    = (const float*)d_in[3];
    const float* gb    = (const float*)d_in[4];
    const float* ww    = (const float*)d_in[5];
    const float* gamma = (const float*)d_in[6];
    const float* beta  = (const float*)d_in[7];

    float* out0 = (float*)d_out;
    float* out1 = out0 + (size_t)B * CA * H * W_;   // B*2*HS*WS ints as floats
    float* out2 = out1 + (size_t)B * 2 * HS * WS;   // B*2

    float* wsf = (float*)d_ws;
    size_t off = 0;
    float* fds     = wsf + off; off += (size_t)B * CM * HS * WS;       // 2,097,152
    float* ssq     = wsf + off; off += (size_t)B * HS * WS;            // 16,384
    float* gbuf    = wsf + off; off += (size_t)B * L;                  // 16,384
    float* dgbuf   = wsf + off; off += (size_t)B * L;                  // 16,384
    float* suk     = wsf + off; off += 64;
    float* yall    = wsf + off; off += (size_t)B * CA * H * W_;        // 8,388,608
    float* ywall   = wsf + off; off += (size_t)B * CA * H * W_;        // 8,388,608
    float* meanvar = wsf + off; off += 256;
    float* ST      = wsf + off; off += (size_t)L * L;                  // 16,777,216
    float* WA      = wsf + off; off += (size_t)L * D2;                 // 8,388,608 (shared W/A)
    float* Zb      = wsf + off; off += (size_t)L * D2;                 // 8,388,608

    k_conv_ds<<<dim3(64, 32, 4), dim3(64, 4), 0, stream>>>(f, gw, gb, fds);
    k_ssq<<<dim3(64, 4), 64, 0, stream>>>(fds, ssq);
    k_scale<<<4, 256, 0, stream>>>(unk, suk, out2);
    k_gate<<<dim3(64, 4), 64, 0, stream>>>(unk, ssq, suk, gbuf, dgbuf);

    for (int b = 0; b < B; ++b) {
        k_buildW<<<dim3(64, 32), dim3(64, 4), 0, stream>>>(fds, WA, b);
        k_gemm1<<<dim3(32, 32), 256, 0, stream>>>(WA, gbuf + (size_t)b * L,
                                                  dgbuf + (size_t)b * L, ST);
        k_softmax<<<4096, 256, 0, stream>>>(ST, out1, b);
        k_buildA<<<dim3(64, 32), dim3(64, 4), 0, stream>>>(alpha, WA, b);
        k_gemm2<<<dim3(16, 32), 256, 0, stream>>>(ST, WA, Zb);
        k_gather<<<dim3(128, 128), 128, 0, stream>>>(Zb, yall, b);
    }

    k_yw<<<dim3(2, 128, 4), 256, 0, stream>>>(yall, ww, ywall);
    k_stats<<<128, 256, 0, stream>>>(ywall, meanvar);
    k_final<<<8192, 256, 0, stream>>>(ywall, meanvar, gamma, beta, alpha, out0);
}

// Round 2
// 1488.644 us; speedup vs baseline: 4.3625x; 4.3625x over previous
//
#include <hip/hip_runtime.h>
#include <math.h>

#define B 4
#define CG 256
#define CM 128
#define CA 128
#define H 128
#define W_ 128
#define HS 64
#define WS 64
#define L 4096
#define D1 1152
#define D2 2048
#define DELTA 2e-3f

typedef unsigned short u16;
typedef __attribute__((ext_vector_type(8))) short short8v;
typedef __attribute__((ext_vector_type(4))) float f32x4;

__device__ __forceinline__ float bf2f(u16 x) {
    union { unsigned int u; float f; } v; v.u = ((unsigned int)x) << 16; return v.f;
}
__device__ __forceinline__ u16 f2bf(float x) {
    union { float f; unsigned int u; } v; v.f = x;
    unsigned int r = (v.u + 0x7FFFu + ((v.u >> 16) & 1u)) >> 16;
    return (u16)r;
}
__device__ __forceinline__ void gll16(const void* g, void* l) {
    __builtin_amdgcn_global_load_lds((const __attribute__((address_space(1))) void*)g,
                                     (__attribute__((address_space(3))) void*)l, 16, 0, 0);
}
__device__ __forceinline__ int refl(int i, int n) {
    return i < 0 ? -i : (i >= n ? 2 * n - 2 - i : i);
}

// K0: f_ds = 1x1 conv at even pixels, LDS-staged f strip
__global__ __launch_bounds__(256) void k_conv_ds(const float* __restrict__ f,
                                                 const float* __restrict__ gw,
                                                 const float* __restrict__ gb,
                                                 float* __restrict__ fds) {
    __shared__ float sf[CG * 64];   // 64KB
    int t = threadIdx.x;
    int hs = blockIdx.x, b = blockIdx.y;
    const float* fb = f + (size_t)b * CG * H * W_ + (2 * hs) * W_;
    for (int idx = t; idx < CG * 64; idx += 256) {
        int ci = idx >> 6, ws = idx & 63;
        sf[idx] = fb[(size_t)ci * H * W_ + 2 * ws];
    }
    __syncthreads();
    int ws = t & 63;
    int wave = __builtin_amdgcn_readfirstlane(t >> 6);
    const float* gwp = gw + (size_t)(wave * 32) * CG;
    float acc[32];
#pragma unroll
    for (int r = 0; r < 32; ++r) acc[r] = gb[wave * 32 + r];
    for (int ci = 0; ci < CG; ++ci) {
        float fv = sf[ci * 64 + ws];
#pragma unroll
        for (int r = 0; r < 32; ++r) acc[r] += gwp[r * CG + ci] * fv;
    }
#pragma unroll
    for (int r = 0; r < 32; ++r) {
        int co = wave * 32 + r;
        fds[(((size_t)b * CM + co) * HS + hs) * WS + ws] = acc[r];
    }
}

__global__ __launch_bounds__(64) void k_ssq(const float* __restrict__ fds,
                                            float* __restrict__ ssq) {
    int ws = threadIdx.x, hs = blockIdx.x, b = blockIdx.y;
    float s = 0.f;
    for (int c = 0; c < CM; ++c) {
        float v = fds[(((size_t)b * CM + c) * HS + hs) * WS + ws];
        s += v * v;
    }
    ssq[((size_t)b * HS + hs) * WS + ws] = s;
}

__global__ __launch_bounds__(256) void k_scale(const float* __restrict__ unk,
                                               float* __restrict__ suk,
                                               float* __restrict__ out2) {
    int b = blockIdx.x, t = threadIdx.x;
    __shared__ float red[256];
    float s = 0.f;
    for (int i = t; i < L; i += 256) {
        int hs = i >> 6, ws = i & 63;
        s += unk[(size_t)b * H * W_ + (2 * hs) * W_ + 2 * ws];
    }
    red[t] = s;
    __syncthreads();
    for (int o = 128; o > 0; o >>= 1) {
        if (t < o) red[t] += red[t + o];
        __syncthreads();
    }
    if (t == 0) {
        float u = red[0] / (float)L;
        float k = 1.0f - u;
        float su = sqrtf(u / k); su = fminf(fmaxf(su, 0.1f), 10.0f);
        float sk = sqrtf(k / u); sk = fminf(fmaxf(sk, 0.1f), 10.0f);
        suk[b * 2] = su; suk[b * 2 + 1] = sk;
        out2[b * 2] = su; out2[b * 2 + 1] = sk;
    }
}

__global__ __launch_bounds__(64) void k_gate(const float* __restrict__ unk,
                                             const float* __restrict__ ssq,
                                             const float* __restrict__ suk,
                                             float* __restrict__ g,
                                             float* __restrict__ dg) {
    int ws = threadIdx.x, hs = blockIdx.x, b = blockIdx.y;
    float sm = 0.f, sq = 0.f;
    for (int di = -1; di <= 1; ++di) {
        int rh = refl(hs + di, HS);
        for (int dj = -1; dj <= 1; ++dj) {
            int rw = refl(ws + dj, WS);
            sm += unk[(size_t)b * H * W_ + (2 * rh) * W_ + 2 * rw];
            sq += ssq[((size_t)b * HS + rh) * WS + rw];
        }
    }
    float mm   = (sm > 0.0f) ? 1.0f : 0.0f;
    float norm = sqrtf(sq);
    float gate = (mm > 0.0f) ? suk[2 * b] : suk[2 * b + 1];
    int q = hs * WS + ws;
    g[(size_t)b * L + q]  = gate / fmaxf(norm, 1e-4f);
    dg[(size_t)b * L + q] = -10000.0f * mm;
}

// K4: fp32 W + bf16 hi/lo split
__global__ __launch_bounds__(256) void k_buildW(const float* __restrict__ fds,
                                                float* __restrict__ Wf,
                                                u16* __restrict__ Whi,
                                                u16* __restrict__ Wlo, int b) {
    int ws = threadIdx.x;
    int c  = blockIdx.y * 4 + threadIdx.y;
    int hs = blockIdx.x;
    int q = hs * WS + ws;
    size_t base = (size_t)q * D1 + c * 9;
    const float* src = fds + ((size_t)b * CM + c) * HS * WS;
#pragma unroll
    for (int i = 0; i < 3; ++i) {
        int rh = refl(hs + i - 1, HS);
#pragma unroll
        for (int j = 0; j < 3; ++j) {
            int rw = refl(ws + j - 1, WS);
            float v = src[rh * WS + rw];
            u16 h = f2bf(v);
            Wf[base + i * 3 + j]  = v;
            Whi[base + i * 3 + j] = h;
            Wlo[base + i * 3 + j] = f2bf(v - bf2f(h));
        }
    }
}

// K5: split-bf16 MFMA score GEMM: ST[p,q] = (W[p].W[q])*g[q] (+diag)
__global__ __launch_bounds__(256) void k_gemm1(const u16* __restrict__ Whi,
                                               const u16* __restrict__ Wlo,
                                               const float* __restrict__ g,
                                               const float* __restrict__ dg,
                                               float* __restrict__ ST) {
    __shared__ u16 sAh[128 * 32], sAl[128 * 32], sBh[128 * 32], sBl[128 * 32];
    int tid = threadIdx.x;
    int wv = tid >> 6, lane = tid & 63;
    int pTile = blockIdx.y * 128, qTile = blockIdx.x * 128;
    int wp = (wv >> 1) * 64, wq = (wv & 1) * 64;
    int r0 = wv * 32;
    int lrow = lane >> 2, lk = (lane & 3) * 8;
    int fr = lane & 15, fq = lane >> 4;

    f32x4 acc[4][4];
#pragma unroll
    for (int mi = 0; mi < 4; ++mi)
#pragma unroll
        for (int ni = 0; ni < 4; ++ni)
#pragma unroll
            for (int r = 0; r < 4; ++r) acc[mi][ni][r] = 0.f;

    for (int k0 = 0; k0 < D1; k0 += 32) {
        __syncthreads();
        const u16* gA = Whi + (size_t)(pTile + r0 + lrow) * D1 + k0 + lk;
        gll16(gA, &sAh[r0 * 32]);
        gll16(gA + (size_t)16 * D1, &sAh[(r0 + 16) * 32]);
        const u16* gAl = Wlo + (size_t)(pTile + r0 + lrow) * D1 + k0 + lk;
        gll16(gAl, &sAl[r0 * 32]);
        gll16(gAl + (size_t)16 * D1, &sAl[(r0 + 16) * 32]);
        const u16* gB = Whi + (size_t)(qTile + r0 + lrow) * D1 + k0 + lk;
        gll16(gB, &sBh[r0 * 32]);
        gll16(gB + (size_t)16 * D1, &sBh[(r0 + 16) * 32]);
        const u16* gBl = Wlo + (size_t)(qTile + r0 + lrow) * D1 + k0 + lk;
        gll16(gBl, &sBl[r0 * 32]);
        gll16(gBl + (size_t)16 * D1, &sBl[(r0 + 16) * 32]);
        __syncthreads();

        short8v ah[4], al[4], bh[4], bl[4];
#pragma unroll
        for (int i = 0; i < 4; ++i) {
            ah[i] = *(const short8v*)&sAh[(wp + i * 16 + fr) * 32 + fq * 8];
            al[i] = *(const short8v*)&sAl[(wp + i * 16 + fr) * 32 + fq * 8];
            bh[i] = *(const short8v*)&sBh[(wq + i * 16 + fr) * 32 + fq * 8];
            bl[i] = *(const short8v*)&sBl[(wq + i * 16 + fr) * 32 + fq * 8];
        }
#pragma unroll
        for (int mi = 0; mi < 4; ++mi)
#pragma unroll
            for (int ni = 0; ni < 4; ++ni) {
                acc[mi][ni] = __builtin_amdgcn_mfma_f32_16x16x32_bf16(ah[mi], bh[ni], acc[mi][ni], 0, 0, 0);
                acc[mi][ni] = __builtin_amdgcn_mfma_f32_16x16x32_bf16(ah[mi], bl[ni], acc[mi][ni], 0, 0, 0);
                acc[mi][ni] = __builtin_amdgcn_mfma_f32_16x16x32_bf16(al[mi], bh[ni], acc[mi][ni], 0, 0, 0);
            }
    }

#pragma unroll
    for (int ni = 0; ni < 4; ++ni) {
        int qq = qTile + wq + ni * 16 + fr;
        float gq = g[qq];
        float dq = dg[qq];
#pragma unroll
        for (int mi = 0; mi < 4; ++mi) {
            int pB = pTile + wp + mi * 16 + fq * 4;
#pragma unroll
            for (int r = 0; r < 4; ++r) {
                int p = pB + r;
                float v = acc[mi][ni][r] * gq;
                if (p == qq) v += dq;
                ST[(size_t)p * L + qq] = v;
            }
        }
    }
}

// K6: argmax(top-2 + exact refinement) + softmax -> bf16 P
__global__ __launch_bounds__(256) void k_softmax(const float* __restrict__ ST,
                                                 u16* __restrict__ Pbf,
                                                 const float* __restrict__ Wf,
                                                 const float* __restrict__ g,
                                                 const float* __restrict__ dg,
                                                 float* __restrict__ out1, int b) {
    __shared__ float buf[L];
    __shared__ float sv1[256], sv2[256];
    __shared__ int   si1[256], si2[256];
    __shared__ float red1[256], red2[256];
    int p = blockIdx.x, t = threadIdx.x;
    const float* rowp = ST + (size_t)p * L;
    float v1 = -3.4e38f, v2 = -3.4e38f; int i1 = L, i2 = L;
    for (int i = t; i < L; i += 256) {
        float v = rowp[i];
        buf[i] = v;
        if (v > v1) { v2 = v1; i2 = i1; v1 = v; i1 = i; }
        else if (v > v2) { v2 = v; i2 = i; }
    }
    sv1[t] = v1; si1[t] = i1; sv2[t] = v2; si2[t] = i2;
    __syncthreads();
    for (int o = 128; o > 0; o >>= 1) {
        if (t < o) {
            float av1 = sv1[t], av2 = sv2[t]; int ai1 = si1[t], ai2 = si2[t];
            float bv1 = sv1[t + o], bv2 = sv2[t + o]; int bi1 = si1[t + o], bi2 = si2[t + o];
            float nv1, nv2; int ni1, ni2;
            bool bfirst = (bv1 > av1) || (bv1 == av1 && bi1 < ai1);
            if (bfirst) {
                nv1 = bv1; ni1 = bi1;
                if ((av1 > bv2) || (av1 == bv2 && ai1 < bi2)) { nv2 = av1; ni2 = ai1; }
                else { nv2 = bv2; ni2 = bi2; }
            } else {
                nv1 = av1; ni1 = ai1;
                if ((bv1 > av2) || (bv1 == av2 && bi1 < ai2)) { nv2 = bv1; ni2 = bi1; }
                else { nv2 = av2; ni2 = ai2; }
            }
            sv1[t] = nv1; si1[t] = ni1; sv2[t] = nv2; si2[t] = ni2;
        }
        __syncthreads();
    }
    float gmax = sv1[0]; int gi1 = si1[0];
    float gv2  = sv2[0]; int gi2 = si2[0];

    float s = 0.f;
    for (int i = t; i < L; i += 256) s += __expf(buf[i] - gmax);
    red1[t] = s;
    __syncthreads();
    for (int o = 128; o > 0; o >>= 1) {
        if (t < o) red1[t] += red1[t + o];
        __syncthreads();
    }
    float inv = 1.0f / red1[0];
    for (int i = t; i < L; i += 256)
        Pbf[(size_t)p * L + i] = f2bf(__expf(buf[i] - gmax) * inv);

    int winner = gi1;
    if (gmax - gv2 < DELTA) {
        __syncthreads();   // red1 reuse
        const float* wp_ = Wf + (size_t)p * D1;
        const float* w1  = Wf + (size_t)gi1 * D1;
        const float* w2  = Wf + (size_t)gi2 * D1;
        float s1 = 0.f, s2 = 0.f;
        for (int k = t; k < D1; k += 256) { float a = wp_[k]; s1 += a * w1[k]; s2 += a * w2[k]; }
        red1[t] = s1; red2[t] = s2;
        __syncthreads();
        for (int o = 128; o > 0; o >>= 1) {
            if (t < o) { red1[t] += red1[t + o]; red2[t] += red2[t + o]; }
            __syncthreads();
        }
        if (t == 0) {
            float e1 = red1[0] * g[gi1] + (p == gi1 ? dg[gi1] : 0.f);
            float e2 = red2[0] * g[gi2] + (p == gi2 ? dg[gi2] : 0.f);
            if (e2 > e1 || (e2 == e1 && gi2 < gi1)) winner = gi2;
            out1[(size_t)(b * 2 + 0) * L + p] = (float)(winner / WS - 32);
            out1[(size_t)(b * 2 + 1) * L + p] = (float)(winner % WS - 32);
        }
    } else if (t == 0) {
        out1[(size_t)(b * 2 + 0) * L + p] = (float)(winner / WS - 32);
        out1[(size_t)(b * 2 + 1) * L + p] = (float)(winner % WS - 32);
    }
}

// K7: At[n,q] = bf16(alpha patch), transposed so GEMM2 is bt-form
__global__ __launch_bounds__(256) void k_buildA(const float* __restrict__ alpha,
                                                u16* __restrict__ At, int b) {
    int q = blockIdx.x * 256 + threadIdx.x;
    int n = blockIdx.y;
    int hs = q >> 6, ws = q & 63;
    int c = n >> 4, ki = (n >> 2) & 3, kj = n & 3;
    int rh = refl(2 * hs + ki - 1, H);
    int rw = refl(2 * ws + kj - 1, W_);
    At[(size_t)n * L + q] = f2bf(alpha[((size_t)b * CA + c) * H * W_ + rh * W_ + rw]);
}

// K8: bf16 MFMA paste GEMM: Z[p,n] = sum_q P[p,q]*At[n,q]
__global__ __launch_bounds__(256) void k_gemm2(const u16* __restrict__ P,
                                               const u16* __restrict__ At,
                                               u16* __restrict__ Z) {
    __shared__ u16 sA[128 * 32], sB[128 * 32];
    int tid = threadIdx.x;
    int wv = tid >> 6, lane = tid & 63;
    int pTile = blockIdx.y * 128, nTile = blockIdx.x * 128;
    int wp = (wv >> 1) * 64, wn = (wv & 1) * 64;
    int r0 = wv * 32;
    int lrow = lane >> 2, lk = (lane & 3) * 8;
    int fr = lane & 15, fq = lane >> 4;

    f32x4 acc[4][4];
#pragma unroll
    for (int mi = 0; mi < 4; ++mi)
#pragma unroll
        for (int ni = 0; ni < 4; ++ni)
#pragma unroll
            for (int r = 0; r < 4; ++r) acc[mi][ni][r] = 0.f;

    for (int k0 = 0; k0 < L; k0 += 32) {
        __syncthreads();
        const u16* gA = P + (size_t)(pTile + r0 + lrow) * L + k0 + lk;
        gll16(gA, &sA[r0 * 32]);
        gll16(gA + (size_t)16 * L, &sA[(r0 + 16) * 32]);
        const u16* gB = At + (size_t)(nTile + r0 + lrow) * L + k0 + lk;
        gll16(gB, &sB[r0 * 32]);
        gll16(gB + (size_t)16 * L, &sB[(r0 + 16) * 32]);
        __syncthreads();

        short8v a[4], bb[4];
#pragma unroll
        for (int i = 0; i < 4; ++i) {
            a[i]  = *(const short8v*)&sA[(wp + i * 16 + fr) * 32 + fq * 8];
            bb[i] = *(const short8v*)&sB[(wn + i * 16 + fr) * 32 + fq * 8];
        }
#pragma unroll
        for (int mi = 0; mi < 4; ++mi)
#pragma unroll
            for (int ni = 0; ni < 4; ++ni)
                acc[mi][ni] = __builtin_amdgcn_mfma_f32_16x16x32_bf16(a[mi], bb[ni], acc[mi][ni], 0, 0, 0);
    }

#pragma unroll
    for (int mi = 0; mi < 4; ++mi)
#pragma unroll
        for (int ni = 0; ni < 4; ++ni) {
            int n = nTile + wn + ni * 16 + fr;
#pragma unroll
            for (int r = 0; r < 4; ++r) {
                int p = pTile + wp + mi * 16 + fq * 4 + r;
                Z[(size_t)p * D2 + n] = f2bf(acc[mi][ni][r]);
            }
        }
}

// K9: transposed-conv gather (Z bf16)
__global__ __launch_bounds__(128) void k_gather(const u16* __restrict__ Z,
                                                float* __restrict__ yall, int b) {
    int w = threadIdx.x;
    int h = blockIdx.x;
    int c = blockIdx.y;
    float s = 0.f;
#pragma unroll
    for (int ki = 0; ki < 4; ++ki) {
        int num = h + 1 - ki;
        if (num < 0 || (num & 1)) continue;
        int hs = num >> 1;
        if (hs >= HS) continue;
#pragma unroll
        for (int kj = 0; kj < 4; ++kj) {
            int numw = w + 1 - kj;
            if (numw < 0 || (numw & 1)) continue;
            int wsd = numw >> 1;
            if (wsd >= WS) continue;
            s += bf2f(Z[(size_t)(hs * WS + wsd) * D2 + c * 16 + ki * 4 + kj]);
        }
    }
    yall[(((size_t)b * CA + c) * H + h) * W_ + w] = 0.25f * s;
}

__global__ __launch_bounds__(256) void k_yw(const float* __restrict__ yall,
                                            const float* __restrict__ ww,
                                            float* __restrict__ yw) {
    __shared__ float ybuf[CA * 64];
    int t  = threadIdx.x;
    int w0 = blockIdx.x * 64;
    int h  = blockIdx.y;
    int b  = blockIdx.z;
    for (int idx = t; idx < CA * 64; idx += 256) {
        int c = idx >> 6, w = idx & 63;
        ybuf[idx] = yall[(((size_t)b * CA + c) * H + h) * W_ + w0 + w];
    }
    __syncthreads();
    int w = t & 63, og = t >> 6;
    float acc[32];
#pragma unroll
    for (int r = 0; r < 32; ++r) acc[r] = 0.f;
    for (int c = 0; c < CA; ++c) {
        float yv = ybuf[c * 64 + w];
#pragma unroll
        for (int r = 0; r < 32; ++r) acc[r] += ww[(og + 4 * r) * CA + c] * yv;
    }
#pragma unroll
    for (int r = 0; r < 32; ++r) {
        int o = og + 4 * r;
        yw[(((size_t)b * CA + o) * H + h) * W_ + w0 + w] = acc[r];
    }
}

__global__ __launch_bounds__(256) void k_stats(const float* __restrict__ yw,
                                               float* __restrict__ meanvar) {
    int o = blockIdx.x, t = threadIdx.x;
    __shared__ float rs[256], rq[256];
    float s = 0.f, q = 0.f;
    for (int b = 0; b < B; ++b) {
        const float* p = yw + ((size_t)(b * CA + o)) * H * W_;
        for (int i = t; i < H * W_; i += 256) {
            float v = p[i];
            s += v;
            q += v * v;
        }
    }
    rs[t] = s; rq[t] = q;
    __syncthreads();
    for (int off = 128; off > 0; off >>= 1) {
        if (t < off) { rs[t] += rs[t + off]; rq[t] += rq[t + off]; }
        __syncthreads();
    }
    if (t == 0) {
        float n = (float)(B * H * W_);
        float mean = rs[0] / n;
        float var  = rq[0] / n - mean * mean;
        meanvar[o] = mean;
        meanvar[CA + o] = var;
    }
}

__global__ __launch_bounds__(256) void k_final(const float* __restrict__ yw,
                                               const float* __restrict__ meanvar,
                                               const float* __restrict__ gamma,
                                               const float* __restrict__ beta,
                                               const float* __restrict__ alpha,
                                               float* __restrict__ out0) {
    size_t i = ((size_t)blockIdx.x * 256 + threadIdx.x) * 4;
    int c = (int)((i >> 14) & 127);
    float4 v = *(const float4*)(yw + i);
    float4 a = *(const float4*)(alpha + i);
    float mean = meanvar[c];
    float var  = meanvar[CA + c];
    float sc   = rsqrtf(var + 1e-5f) * gamma[c];
    float bt   = beta[c];
    float4 r;
    r.x = (v.x - mean) * sc + bt + a.x;
    r.y = (v.y - mean) * sc + bt + a.y;
    r.z = (v.z - mean) * sc + bt + a.z;
    r.w = (v.w - mean) * sc + bt + a.w;
    *(float4*)(out0 + i) = r;
}

extern "C" void kernel_launch(void* const* d_in, const int* in_sizes, int n_in,
                              void* d_out, int out_size, void* d_ws, size_t ws_size,
                              hipStream_t stream) {
    (void)in_sizes; (void)n_in; (void)out_size; (void)ws_size;
    const float* f     = (const float*)d_in[0];
    const float* alpha = (const float*)d_in[1];
    const float* unk   = (const float*)d_in[2];
    const float* gw    = (const float*)d_in[3];
    const float* gb    = (const float*)d_in[4];
    const float* ww    = (const float*)d_in[5];
    const float* gamma = (const float*)d_in[6];
    const float* beta  = (const float*)d_in[7];

    float* out0 = (float*)d_out;
    float* out1 = out0 + (size_t)B * CA * H * W_;
    float* out2 = out1 + (size_t)B * 2 * HS * WS;

    float* wsf = (float*)d_ws;
    size_t off = 0;
    float* fds   = wsf + off; off += (size_t)B * CM * HS * WS;   // 2,097,152
    float* ssq   = wsf + off; off += (size_t)B * HS * WS;        // 16,384
    float* gbuf  = wsf + off; off += (size_t)B * L;              // 16,384
    float* dgbuf = wsf + off; off += (size_t)B * L;              // 16,384
    float* suk   = wsf + off; off += 64;
    float* ST    = wsf + off; off += (size_t)L * L;              // 16,777,216 (ywall aliases)
    float* ywall = ST;                                           // used after loop
    float* yall  = wsf + off; off += (size_t)B * CA * H * W_;    // 8,388,608
    float* WfZ   = wsf + off; off += (size_t)L * D1;             // 4,718,592 f (Wf fp32 / Zb bf16)
    float* WhiA  = wsf + off; off += (size_t)L * D1;             // 4,718,592 f (Whi+Wlo / Atb)
    float* PbfF  = wsf + off; off += (size_t)L * L / 2;          // 8,388,608 f (Pbf bf16)
    float* meanvar = wsf + off; off += 256;

    float* Wf  = WfZ;
    u16*   Zb  = (u16*)WfZ;
    u16*   Whi = (u16*)WhiA;
    u16*   Wlo = Whi + (size_t)L * D1;
    u16*   Atb = (u16*)WhiA;
    u16*   Pbf = (u16*)PbfF;

    k_conv_ds<<<dim3(64, 4), 256, 0, stream>>>(f, gw, gb, fds);
    k_ssq<<<dim3(64, 4), 64, 0, stream>>>(fds, ssq);
    k_scale<<<4, 256, 0, stream>>>(unk, suk, out2);
    k_gate<<<dim3(64, 4), 64, 0, stream>>>(unk, ssq, suk, gbuf, dgbuf);

    for (int b = 0; b < B; ++b) {
        k_buildW<<<dim3(64, 32), dim3(64, 4), 0, stream>>>(fds, Wf, Whi, Wlo, b);
        k_gemm1<<<dim3(32, 32), 256, 0, stream>>>(Whi, Wlo, gbuf + (size_t)b * L,
                                                  dgbuf + (size_t)b * L, ST);
        k_softmax<<<4096, 256, 0, stream>>>(ST, Pbf, Wf, gbuf + (size_t)b * L,
                                            dgbuf + (size_t)b * L, out1, b);
        k_buildA<<<dim3(16, 2048), 256, 0, stream>>>(alpha, Atb, b);
        k_gemm2<<<dim3(16, 32), 256, 0, stream>>>(Pbf, Atb, Zb);
        k_gather<<<dim3(128, 128), 128, 0, stream>>>(Zb, yall, b);
    }

    k_yw<<<dim3(2, 128, 4), 256, 0, stream>>>(yall, ww, ywall);
    k_stats<<<128, 256, 0, stream>>>(ywall, meanvar);
    k_final<<<8192, 256, 0, stream>>>(ywall, meanvar, gamma, beta, alpha, out0);
}

// Round 3
// 1287.535 us; speedup vs baseline: 5.0439x; 1.1562x over previous
//
#include <hip/hip_runtime.h>
#include <math.h>

#define B 4
#define CG 256
#define CM 128
#define CA 128
#define H 128
#define W_ 128
#define HS 64
#define WS 64
#define L 4096
#define D1 1152
#define D2 2048
#define NPIX 65536   // B*H*W/... = B*16384
#define DELTA 2e-3f

typedef unsigned short u16;
typedef __attribute__((ext_vector_type(8))) short short8v;
typedef __attribute__((ext_vector_type(4))) float f32x4;

__device__ __forceinline__ float bf2f(u16 x) {
    union { unsigned int u; float f; } v; v.u = ((unsigned int)x) << 16; return v.f;
}
__device__ __forceinline__ u16 f2bf(float x) {
    union { float f; unsigned int u; } v; v.f = x;
    unsigned int r = (v.u + 0x7FFFu + ((v.u >> 16) & 1u)) >> 16;
    return (u16)r;
}
__device__ __forceinline__ void gll16(const void* g, void* l) {
    __builtin_amdgcn_global_load_lds((const __attribute__((address_space(1))) void*)g,
                                     (__attribute__((address_space(3))) void*)l, 16, 0, 0);
}
__device__ __forceinline__ int refl(int i, int n) {
    return i < 0 ? -i : (i >= n ? 2 * n - 2 - i : i);
}

// K0: f_ds = 1x1 conv at even pixels, LDS-staged f strip
__global__ __launch_bounds__(256) void k_conv_ds(const float* __restrict__ f,
                                                 const float* __restrict__ gw,
                                                 const float* __restrict__ gb,
                                                 float* __restrict__ fds) {
    __shared__ float sf[CG * 64];
    int t = threadIdx.x;
    int hs = blockIdx.x, b = blockIdx.y;
    const float* fb = f + (size_t)b * CG * H * W_ + (2 * hs) * W_;
    for (int idx = t; idx < CG * 64; idx += 256) {
        int ci = idx >> 6, ws = idx & 63;
        sf[idx] = fb[(size_t)ci * H * W_ + 2 * ws];
    }
    __syncthreads();
    int ws = t & 63;
    int wave = __builtin_amdgcn_readfirstlane(t >> 6);
    const float* gwp = gw + (size_t)(wave * 32) * CG;
    float acc[32];
#pragma unroll
    for (int r = 0; r < 32; ++r) acc[r] = gb[wave * 32 + r];
    for (int ci = 0; ci < CG; ++ci) {
        float fv = sf[ci * 64 + ws];
#pragma unroll
        for (int r = 0; r < 32; ++r) acc[r] += gwp[r * CG + ci] * fv;
    }
#pragma unroll
    for (int r = 0; r < 32; ++r) {
        int co = wave * 32 + r;
        fds[(((size_t)b * CM + co) * HS + hs) * WS + ws] = acc[r];
    }
}

__global__ __launch_bounds__(64) void k_ssq(const float* __restrict__ fds,
                                            float* __restrict__ ssq) {
    int ws = threadIdx.x, hs = blockIdx.x, b = blockIdx.y;
    float s = 0.f;
    for (int c = 0; c < CM; ++c) {
        float v = fds[(((size_t)b * CM + c) * HS + hs) * WS + ws];
        s += v * v;
    }
    ssq[((size_t)b * HS + hs) * WS + ws] = s;
}

__global__ __launch_bounds__(256) void k_scale(const float* __restrict__ unk,
                                               float* __restrict__ suk,
                                               float* __restrict__ out2) {
    int b = blockIdx.x, t = threadIdx.x;
    __shared__ float red[256];
    float s = 0.f;
    for (int i = t; i < L; i += 256) {
        int hs = i >> 6, ws = i & 63;
        s += unk[(size_t)b * H * W_ + (2 * hs) * W_ + 2 * ws];
    }
    red[t] = s;
    __syncthreads();
    for (int o = 128; o > 0; o >>= 1) {
        if (t < o) red[t] += red[t + o];
        __syncthreads();
    }
    if (t == 0) {
        float u = red[0] / (float)L;
        float k = 1.0f - u;
        float su = sqrtf(u / k); su = fminf(fmaxf(su, 0.1f), 10.0f);
        float sk = sqrtf(k / u); sk = fminf(fmaxf(sk, 0.1f), 10.0f);
        suk[b * 2] = su; suk[b * 2 + 1] = sk;
        out2[b * 2] = su; out2[b * 2 + 1] = sk;
    }
}

__global__ __launch_bounds__(64) void k_gate(const float* __restrict__ unk,
                                             const float* __restrict__ ssq,
                                             const float* __restrict__ suk,
                                             float* __restrict__ g,
                                             float* __restrict__ dg) {
    int ws = threadIdx.x, hs = blockIdx.x, b = blockIdx.y;
    float sm = 0.f, sq = 0.f;
    for (int di = -1; di <= 1; ++di) {
        int rh = refl(hs + di, HS);
        for (int dj = -1; dj <= 1; ++dj) {
            int rw = refl(ws + dj, WS);
            sm += unk[(size_t)b * H * W_ + (2 * rh) * W_ + 2 * rw];
            sq += ssq[((size_t)b * HS + rh) * WS + rw];
        }
    }
    float mm   = (sm > 0.0f) ? 1.0f : 0.0f;
    float norm = sqrtf(sq);
    float gate = (mm > 0.0f) ? suk[2 * b] : suk[2 * b + 1];
    int q = hs * WS + ws;
    g[(size_t)b * L + q]  = gate / fmaxf(norm, 1e-4f);
    dg[(size_t)b * L + q] = -10000.0f * mm;
}

// K4: fp32 W + bf16 hi/lo split
__global__ __launch_bounds__(256) void k_buildW(const float* __restrict__ fds,
                                                float* __restrict__ Wf,
                                                u16* __restrict__ Whi,
                                                u16* __restrict__ Wlo, int b) {
    int ws = threadIdx.x;
    int c  = blockIdx.y * 4 + threadIdx.y;
    int hs = blockIdx.x;
    int q = hs * WS + ws;
    size_t base = (size_t)q * D1 + c * 9;
    const float* src = fds + ((size_t)b * CM + c) * HS * WS;
#pragma unroll
    for (int i = 0; i < 3; ++i) {
        int rh = refl(hs + i - 1, HS);
#pragma unroll
        for (int j = 0; j < 3; ++j) {
            int rw = refl(ws + j - 1, WS);
            float v = src[rh * WS + rw];
            u16 h = f2bf(v);
            Wf[base + i * 3 + j]  = v;
            Whi[base + i * 3 + j] = h;
            Wlo[base + i * 3 + j] = f2bf(v - bf2f(h));
        }
    }
}

// K5: symmetric split-bf16 MFMA score GEMM (upper-triangle blocks + mirror)
__global__ __launch_bounds__(256) void k_gemm1(const u16* __restrict__ Whi,
                                               const u16* __restrict__ Wlo,
                                               const float* __restrict__ g,
                                               const float* __restrict__ dg,
                                               float* __restrict__ ST) {
    __shared__ u16 sAh[128 * 32], sAl[128 * 32], sBh[128 * 32], sBl[128 * 32];
    int tid = threadIdx.x;
    int wv = tid >> 6, lane = tid & 63;
    // unrank upper-triangle pair (I,J), I<=J<32
    int t = blockIdx.x, I = 0;
    while (t >= 32 - I) { t -= 32 - I; ++I; }
    int J = I + t;
    int pTile = I * 128, qTile = J * 128;
    int wp = (wv >> 1) * 64, wq = (wv & 1) * 64;
    int r0 = wv * 32;
    int lrow = lane >> 2, lk = (lane & 3) * 8;
    int fr = lane & 15, fq = lane >> 4;

    f32x4 acc[4][4];
#pragma unroll
    for (int mi = 0; mi < 4; ++mi)
#pragma unroll
        for (int ni = 0; ni < 4; ++ni)
#pragma unroll
            for (int r = 0; r < 4; ++r) acc[mi][ni][r] = 0.f;

    for (int k0 = 0; k0 < D1; k0 += 32) {
        __syncthreads();
        const u16* gA = Whi + (size_t)(pTile + r0 + lrow) * D1 + k0 + lk;
        gll16(gA, &sAh[r0 * 32]);
        gll16(gA + (size_t)16 * D1, &sAh[(r0 + 16) * 32]);
        const u16* gAl = Wlo + (size_t)(pTile + r0 + lrow) * D1 + k0 + lk;
        gll16(gAl, &sAl[r0 * 32]);
        gll16(gAl + (size_t)16 * D1, &sAl[(r0 + 16) * 32]);
        const u16* gB = Whi + (size_t)(qTile + r0 + lrow) * D1 + k0 + lk;
        gll16(gB, &sBh[r0 * 32]);
        gll16(gB + (size_t)16 * D1, &sBh[(r0 + 16) * 32]);
        const u16* gBl = Wlo + (size_t)(qTile + r0 + lrow) * D1 + k0 + lk;
        gll16(gBl, &sBl[r0 * 32]);
        gll16(gBl + (size_t)16 * D1, &sBl[(r0 + 16) * 32]);
        __syncthreads();

        short8v ah[4], al[4], bh[4], bl[4];
#pragma unroll
        for (int i = 0; i < 4; ++i) {
            ah[i] = *(const short8v*)&sAh[(wp + i * 16 + fr) * 32 + fq * 8];
            al[i] = *(const short8v*)&sAl[(wp + i * 16 + fr) * 32 + fq * 8];
            bh[i] = *(const short8v*)&sBh[(wq + i * 16 + fr) * 32 + fq * 8];
            bl[i] = *(const short8v*)&sBl[(wq + i * 16 + fr) * 32 + fq * 8];
        }
#pragma unroll
        for (int mi = 0; mi < 4; ++mi)
#pragma unroll
            for (int ni = 0; ni < 4; ++ni) {
                acc[mi][ni] = __builtin_amdgcn_mfma_f32_16x16x32_bf16(ah[mi], bh[ni], acc[mi][ni], 0, 0, 0);
                acc[mi][ni] = __builtin_amdgcn_mfma_f32_16x16x32_bf16(ah[mi], bl[ni], acc[mi][ni], 0, 0, 0);
                acc[mi][ni] = __builtin_amdgcn_mfma_f32_16x16x32_bf16(al[mi], bh[ni], acc[mi][ni], 0, 0, 0);
            }
    }

    // direct tile: rows p (I), cols q (J)
#pragma unroll
    for (int ni = 0; ni < 4; ++ni) {
        int qq = qTile + wq + ni * 16 + fr;
        float gq = g[qq];
        float dq = dg[qq];
#pragma unroll
        for (int mi = 0; mi < 4; ++mi) {
            int pB = pTile + wp + mi * 16 + fq * 4;
#pragma unroll
            for (int r = 0; r < 4; ++r) {
                int p = pB + r;
                float v = acc[mi][ni][r] * gq;
                if (p == qq) v += dq;
                ST[(size_t)p * L + qq] = v;
            }
        }
    }
    // mirror tile: rows q (J), cols p (I)
    if (I != J) {
#pragma unroll
        for (int mi = 0; mi < 4; ++mi) {
            int p0 = pTile + wp + mi * 16 + fq * 4;
            float gp0 = g[p0], gp1 = g[p0 + 1], gp2 = g[p0 + 2], gp3 = g[p0 + 3];
#pragma unroll
            for (int ni = 0; ni < 4; ++ni) {
                int qq = qTile + wq + ni * 16 + fr;
                *(float4*)(ST + (size_t)qq * L + p0) =
                    make_float4(acc[mi][ni][0] * gp0, acc[mi][ni][1] * gp1,
                                acc[mi][ni][2] * gp2, acc[mi][ni][3] * gp3);
            }
        }
    }
}

// K6: argmax(top-2 + exact refinement) + softmax -> bf16 P
__global__ __launch_bounds__(256) void k_softmax(const float* __restrict__ ST,
                                                 u16* __restrict__ Pbf,
                                                 const float* __restrict__ Wf,
                                                 const float* __restrict__ g,
                                                 const float* __restrict__ dg,
                                                 float* __restrict__ out1, int b) {
    __shared__ float buf[L];
    __shared__ float sv1[256], sv2[256];
    __shared__ int   si1[256], si2[256];
    __shared__ float red1[256], red2[256];
    int p = blockIdx.x, t = threadIdx.x;
    const float* rowp = ST + (size_t)p * L;
    float v1 = -3.4e38f, v2 = -3.4e38f; int i1 = L, i2 = L;
    for (int i = t; i < L; i += 256) {
        float v = rowp[i];
        buf[i] = v;
        if (v > v1) { v2 = v1; i2 = i1; v1 = v; i1 = i; }
        else if (v > v2) { v2 = v; i2 = i; }
    }
    sv1[t] = v1; si1[t] = i1; sv2[t] = v2; si2[t] = i2;
    __syncthreads();
    for (int o = 128; o > 0; o >>= 1) {
        if (t < o) {
            float av1 = sv1[t], av2 = sv2[t]; int ai1 = si1[t], ai2 = si2[t];
            float bv1 = sv1[t + o], bv2 = sv2[t + o]; int bi1 = si1[t + o], bi2 = si2[t + o];
            float nv1, nv2; int ni1, ni2;
            bool bfirst = (bv1 > av1) || (bv1 == av1 && bi1 < ai1);
            if (bfirst) {
                nv1 = bv1; ni1 = bi1;
                if ((av1 > bv2) || (av1 == bv2 && ai1 < bi2)) { nv2 = av1; ni2 = ai1; }
                else { nv2 = bv2; ni2 = bi2; }
            } else {
                nv1 = av1; ni1 = ai1;
                if ((bv1 > av2) || (bv1 == av2 && bi1 < ai2)) { nv2 = bv1; ni2 = bi1; }
                else { nv2 = av2; ni2 = ai2; }
            }
            sv1[t] = nv1; si1[t] = ni1; sv2[t] = nv2; si2[t] = ni2;
        }
        __syncthreads();
    }
    float gmax = sv1[0]; int gi1 = si1[0];
    float gv2  = sv2[0]; int gi2 = si2[0];

    float s = 0.f;
    for (int i = t; i < L; i += 256) {
        float e = __expf(buf[i] - gmax);
        buf[i] = e;
        s += e;
    }
    red1[t] = s;
    __syncthreads();
    for (int o = 128; o > 0; o >>= 1) {
        if (t < o) red1[t] += red1[t + o];
        __syncthreads();
    }
    float inv = 1.0f / red1[0];
    for (int i = t; i < L; i += 256)
        Pbf[(size_t)p * L + i] = f2bf(buf[i] * inv);

    int winner = gi1;
    if (gmax - gv2 < DELTA) {
        __syncthreads();
        const float* wp_ = Wf + (size_t)p * D1;
        const float* w1  = Wf + (size_t)gi1 * D1;
        const float* w2  = Wf + (size_t)gi2 * D1;
        float s1 = 0.f, s2 = 0.f;
        for (int k = t; k < D1; k += 256) { float a = wp_[k]; s1 += a * w1[k]; s2 += a * w2[k]; }
        red1[t] = s1; red2[t] = s2;
        __syncthreads();
        for (int o = 128; o > 0; o >>= 1) {
            if (t < o) { red1[t] += red1[t + o]; red2[t] += red2[t + o]; }
            __syncthreads();
        }
        if (t == 0) {
            float e1 = red1[0] * g[gi1] + (p == gi1 ? dg[gi1] : 0.f);
            float e2 = red2[0] * g[gi2] + (p == gi2 ? dg[gi2] : 0.f);
            if (e2 > e1 || (e2 == e1 && gi2 < gi1)) winner = gi2;
            out1[(size_t)(b * 2 + 0) * L + p] = (float)(winner / WS - 32);
            out1[(size_t)(b * 2 + 1) * L + p] = (float)(winner % WS - 32);
        }
    } else if (t == 0) {
        out1[(size_t)(b * 2 + 0) * L + p] = (float)(winner / WS - 32);
        out1[(size_t)(b * 2 + 1) * L + p] = (float)(winner % WS - 32);
    }
}

// K7: At[n,q] = bf16(alpha patch), transposed so GEMM2 is bt-form
__global__ __launch_bounds__(256) void k_buildA(const float* __restrict__ alpha,
                                                u16* __restrict__ At, int b) {
    int q = blockIdx.x * 256 + threadIdx.x;
    int n = blockIdx.y;
    int hs = q >> 6, ws = q & 63;
    int c = n >> 4, ki = (n >> 2) & 3, kj = n & 3;
    int rh = refl(2 * hs + ki - 1, H);
    int rw = refl(2 * ws + kj - 1, W_);
    At[(size_t)n * L + q] = f2bf(alpha[((size_t)b * CA + c) * H * W_ + rh * W_ + rw]);
}

// K8: bf16 MFMA paste GEMM: Z[p,n] = sum_q P[p,q]*At[n,q]
__global__ __launch_bounds__(256) void k_gemm2(const u16* __restrict__ P,
                                               const u16* __restrict__ At,
                                               u16* __restrict__ Z) {
    __shared__ u16 sA[128 * 32], sB[128 * 32];
    int tid = threadIdx.x;
    int wv = tid >> 6, lane = tid & 63;
    int pTile = blockIdx.y * 128, nTile = blockIdx.x * 128;
    int wp = (wv >> 1) * 64, wn = (wv & 1) * 64;
    int r0 = wv * 32;
    int lrow = lane >> 2, lk = (lane & 3) * 8;
    int fr = lane & 15, fq = lane >> 4;

    f32x4 acc[4][4];
#pragma unroll
    for (int mi = 0; mi < 4; ++mi)
#pragma unroll
        for (int ni = 0; ni < 4; ++ni)
#pragma unroll
            for (int r = 0; r < 4; ++r) acc[mi][ni][r] = 0.f;

    for (int k0 = 0; k0 < L; k0 += 32) {
        __syncthreads();
        const u16* gA = P + (size_t)(pTile + r0 + lrow) * L + k0 + lk;
        gll16(gA, &sA[r0 * 32]);
        gll16(gA + (size_t)16 * L, &sA[(r0 + 16) * 32]);
        const u16* gB = At + (size_t)(nTile + r0 + lrow) * L + k0 + lk;
        gll16(gB, &sB[r0 * 32]);
        gll16(gB + (size_t)16 * L, &sB[(r0 + 16) * 32]);
        __syncthreads();

        short8v a[4], bb[4];
#pragma unroll
        for (int i = 0; i < 4; ++i) {
            a[i]  = *(const short8v*)&sA[(wp + i * 16 + fr) * 32 + fq * 8];
            bb[i] = *(const short8v*)&sB[(wn + i * 16 + fr) * 32 + fq * 8];
        }
#pragma unroll
        for (int mi = 0; mi < 4; ++mi)
#pragma unroll
            for (int ni = 0; ni < 4; ++ni)
                acc[mi][ni] = __builtin_amdgcn_mfma_f32_16x16x32_bf16(a[mi], bb[ni], acc[mi][ni], 0, 0, 0);
    }

#pragma unroll
    for (int mi = 0; mi < 4; ++mi)
#pragma unroll
        for (int ni = 0; ni < 4; ++ni) {
            int n = nTile + wn + ni * 16 + fr;
#pragma unroll
            for (int r = 0; r < 4; ++r) {
                int p = pTile + wp + mi * 16 + fq * 4 + r;
                Z[(size_t)p * D2 + n] = f2bf(acc[mi][ni][r]);
            }
        }
}

// K9: transposed-conv gather -> yt[pix, c] bf16 (c XOR-swizzled per pix row)
__global__ __launch_bounds__(256) void k_gather(const u16* __restrict__ Z,
                                                u16* __restrict__ yt, int b) {
    int c  = threadIdx.x & 127;
    int pl = threadIdx.x >> 7;
    int w  = blockIdx.x * 2 + pl;
    int h  = blockIdx.y;
    float s = 0.f;
#pragma unroll
    for (int ki = 0; ki < 4; ++ki) {
        int num = h + 1 - ki;
        if (num < 0 || (num & 1)) continue;
        int hs = num >> 1;
        if (hs >= HS) continue;
#pragma unroll
        for (int kj = 0; kj < 4; ++kj) {
            int numw = w + 1 - kj;
            if (numw < 0 || (numw & 1)) continue;
            int wsd = numw >> 1;
            if (wsd >= WS) continue;
            s += bf2f(Z[(size_t)(hs * WS + wsd) * D2 + c * 16 + ki * 4 + kj]);
        }
    }
    int pix = h * W_ + w;
    int cs = c ^ ((pix & 7) << 3);
    yt[((size_t)b * 16384 + pix) * 128 + cs] = f2bf(0.25f * s);
}

// cvt w_w -> bf16, row-swizzled
__global__ __launch_bounds__(256) void k_cvtww(const float* __restrict__ ww,
                                               u16* __restrict__ wwbf) {
    int i = blockIdx.x * 256 + threadIdx.x;
    int o = i >> 7, c = i & 127;
    wwbf[o * 128 + (c ^ ((o & 7) << 3))] = f2bf(ww[i]);
}

// K10: yw[o, gp] = sum_c w_w[o,c] * y[gp, c]   MFMA, K=128, one stage
__global__ __launch_bounds__(256) void k_ywgemm(const u16* __restrict__ wwbf,
                                                const u16* __restrict__ yt,
                                                float* __restrict__ yw) {
    __shared__ u16 sA[128 * 128], sB[128 * 128];
    int tid = threadIdx.x;
    int wv = tid >> 6, lane = tid & 63;
    int nTile = blockIdx.x * 128;
    int wp = (wv >> 1) * 64, wn = (wv & 1) * 64;
    int fr = lane & 15, fq = lane >> 4;

    const u16* gB = yt + (size_t)nTile * 128;
#pragma unroll
    for (int i = 0; i < 8; ++i) {
        int o = (i * 4 + wv) * 512;
        gll16(wwbf + o + lane * 8, &sA[o]);
        gll16(gB + o + lane * 8, &sB[o]);
    }
    __syncthreads();

    f32x4 acc[4][4];
#pragma unroll
    for (int mi = 0; mi < 4; ++mi)
#pragma unroll
        for (int ni = 0; ni < 4; ++ni)
#pragma unroll
            for (int r = 0; r < 4; ++r) acc[mi][ni][r] = 0.f;

#pragma unroll
    for (int ks = 0; ks < 4; ++ks) {
        int k0 = ks * 32 + fq * 8;
        short8v a[4], bb[4];
#pragma unroll
        for (int i = 0; i < 4; ++i) {
            int ra = wp + i * 16 + fr;
            a[i] = *(const short8v*)&sA[ra * 128 + (k0 ^ ((ra & 7) << 3))];
            int rb = wn + i * 16 + fr;
            bb[i] = *(const short8v*)&sB[rb * 128 + (k0 ^ ((rb & 7) << 3))];
        }
#pragma unroll
        for (int mi = 0; mi < 4; ++mi)
#pragma unroll
            for (int ni = 0; ni < 4; ++ni)
                acc[mi][ni] = __builtin_amdgcn_mfma_f32_16x16x32_bf16(a[mi], bb[ni], acc[mi][ni], 0, 0, 0);
    }

#pragma unroll
    for (int mi = 0; mi < 4; ++mi)
#pragma unroll
        for (int ni = 0; ni < 4; ++ni) {
            int gp = nTile + wn + ni * 16 + fr;
#pragma unroll
            for (int r = 0; r < 4; ++r) {
                int o = wp + mi * 16 + fq * 4 + r;
                yw[(size_t)o * NPIX + gp] = acc[mi][ni][r];
            }
        }
}

// K10b: per-channel mean/var over all pixels (yw layout [o][NPIX])
__global__ __launch_bounds__(256) void k_stats(const float* __restrict__ yw,
                                               float* __restrict__ meanvar) {
    int o = blockIdx.x, t = threadIdx.x;
    __shared__ float rs[256], rq[256];
    float s = 0.f, q = 0.f;
    const float* p = yw + (size_t)o * NPIX;
    for (int i = t; i < NPIX; i += 256) {
        float v = p[i];
        s += v;
        q += v * v;
    }
    rs[t] = s; rq[t] = q;
    __syncthreads();
    for (int off = 128; off > 0; off >>= 1) {
        if (t < off) { rs[t] += rs[t + off]; rq[t] += rq[t + off]; }
        __syncthreads();
    }
    if (t == 0) {
        float n = (float)NPIX;
        float mean = rs[0] / n;
        float var  = rq[0] / n - mean * mean;
        meanvar[o] = mean;
        meanvar[CA + o] = var;
    }
}

// K11: out0[b,c,pix] = (yw[c, b*16384+pix]-mean)*rsqrt(var+eps)*gamma + beta + alpha
__global__ __launch_bounds__(256) void k_final(const float* __restrict__ yw,
                                               const float* __restrict__ meanvar,
                                               const float* __restrict__ gamma,
                                               const float* __restrict__ beta,
                                               const float* __restrict__ alpha,
                                               float* __restrict__ out0) {
    size_t i = ((size_t)blockIdx.x * 256 + threadIdx.x) * 4;
    int c = (int)((i >> 14) & 127);
    int b = (int)(i >> 21);
    int pix = (int)(i & 16383);
    float4 v = *(const float4*)(yw + (size_t)c * NPIX + b * 16384 + pix);
    float4 a = *(const float4*)(alpha + i);
    float mean = meanvar[c];
    float var  = meanvar[CA + c];
    float sc   = rsqrtf(var + 1e-5f) * gamma[c];
    float bt   = beta[c];
    float4 r;
    r.x = (v.x - mean) * sc + bt + a.x;
    r.y = (v.y - mean) * sc + bt + a.y;
    r.z = (v.z - mean) * sc + bt + a.z;
    r.w = (v.w - mean) * sc + bt + a.w;
    *(float4*)(out0 + i) = r;
}

extern "C" void kernel_launch(void* const* d_in, const int* in_sizes, int n_in,
                              void* d_out, int out_size, void* d_ws, size_t ws_size,
                              hipStream_t stream) {
    (void)in_sizes; (void)n_in; (void)out_size; (void)ws_size;
    const float* f     = (const float*)d_in[0];
    const float* alpha = (const float*)d_in[1];
    const float* unk   = (const float*)d_in[2];
    const float* gw    = (const float*)d_in[3];
    const float* gb    = (const float*)d_in[4];
    const float* ww    = (const float*)d_in[5];
    const float* gamma = (const float*)d_in[6];
    const float* beta  = (const float*)d_in[7];

    float* out0 = (float*)d_out;
    float* out1 = out0 + (size_t)B * CA * H * W_;
    float* out2 = out1 + (size_t)B * 2 * HS * WS;

    float* wsf = (float*)d_ws;
    size_t off = 0;
    float* fds   = wsf + off; off += (size_t)B * CM * HS * WS;   // 2,097,152
    float* ssq   = wsf + off; off += (size_t)B * HS * WS;
    float* gbuf  = wsf + off; off += (size_t)B * L;
    float* dgbuf = wsf + off; off += (size_t)B * L;
    float* suk   = wsf + off; off += 64;
    float* ST    = wsf + off; off += (size_t)L * L;              // 16.78M f (yw aliases)
    float* yw    = ST;                                           // [128][65536] fp32
    float* WfZ   = wsf + off; off += (size_t)L * D1;             // Wf fp32 / Zb bf16
    float* WhiA  = wsf + off; off += (size_t)L * D1;             // Whi+Wlo / Atb
    float* PbfF  = wsf + off; off += (size_t)L * L / 2;          // Pbf bf16
    float* ytF   = wsf + off; off += (size_t)NPIX * 128 / 2;     // yt bf16 [NPIX][128]
    float* wwbfF = wsf + off; off += 8192;
    float* meanvar = wsf + off; off += 256;

    float* Wf   = WfZ;
    u16*   Zb   = (u16*)WfZ;
    u16*   Whi  = (u16*)WhiA;
    u16*   Wlo  = Whi + (size_t)L * D1;
    u16*   Atb  = (u16*)WhiA;
    u16*   Pbf  = (u16*)PbfF;
    u16*   yt   = (u16*)ytF;
    u16*   wwbf = (u16*)wwbfF;

    k_cvtww<<<64, 256, 0, stream>>>(ww, wwbf);
    k_conv_ds<<<dim3(64, 4), 256, 0, stream>>>(f, gw, gb, fds);
    k_ssq<<<dim3(64, 4), 64, 0, stream>>>(fds, ssq);
    k_scale<<<4, 256, 0, stream>>>(unk, suk, out2);
    k_gate<<<dim3(64, 4), 64, 0, stream>>>(unk, ssq, suk, gbuf, dgbuf);

    for (int b = 0; b < B; ++b) {
        k_buildW<<<dim3(64, 32), dim3(64, 4), 0, stream>>>(fds, Wf, Whi, Wlo, b);
        k_gemm1<<<528, 256, 0, stream>>>(Whi, Wlo, gbuf + (size_t)b * L,
                                         dgbuf + (size_t)b * L, ST);
        k_softmax<<<4096, 256, 0, stream>>>(ST, Pbf, Wf, gbuf + (size_t)b * L,
                                            dgbuf + (size_t)b * L, out1, b);
        k_buildA<<<dim3(16, 2048), 256, 0, stream>>>(alpha, Atb, b);
        k_gemm2<<<dim3(16, 32), 256, 0, stream>>>(Pbf, Atb, Zb);
        k_gather<<<dim3(64, 128), 256, 0, stream>>>(Zb, yt, b);
    }

    k_ywgemm<<<512, 256, 0, stream>>>(wwbf, yt, yw);
    k_stats<<<128, 256, 0, stream>>>(yw, meanvar);
    k_final<<<8192, 256, 0, stream>>>(yw, meanvar, gamma, beta, alpha, out0);
}